// Round 8
// baseline (224.695 us; speedup 1.0000x reference)
//
#include <hip/hip_runtime.h>
#include <stdint.h>

typedef unsigned short u16;
typedef __attribute__((ext_vector_type(8))) short short8;   // 8 bf16 (4 VGPRs) MFMA A/B frag K=32
typedef __attribute__((ext_vector_type(4))) short short4v;  // 4 bf16 (2 VGPRs) MFMA A/B frag K=16
typedef __attribute__((ext_vector_type(4))) float float4v;  // MFMA C/D frag

#define NB 2
#define NT 2048
#define NC 1024
#define NH 16
#define ND 64
#define NM (NB*NT)   // 4096 rows total

// 16x16x16 bf16 MFMA (2-VGPR operands). Builtin if present, else raw asm.
#if defined(__has_builtin)
#if __has_builtin(__builtin_amdgcn_mfma_f32_16x16x16bf16_1k)
#define MFMA16(a, b, c) __builtin_amdgcn_mfma_f32_16x16x16bf16_1k(a, b, c, 0, 0, 0)
#endif
#endif
#ifndef MFMA16
static __device__ __forceinline__ float4v mfma16_asm(short4v a, short4v b, float4v c) {
  asm volatile("v_mfma_f32_16x16x16_bf16 %0, %1, %2, %0" : "+v"(c) : "v"(a), "v"(b));
  return c;
}
#define MFMA16(a, b, c) mfma16_asm(a, b, c)
#endif

// wait-for-own-chunk + barrier. vmcnt(4) = the 4 just-issued next-chunk loads stay in flight.
#define WB4 asm volatile("s_waitcnt vmcnt(4)\n\ts_barrier" ::: "memory")
#define WB0 asm volatile("s_waitcnt vmcnt(0)\n\ts_barrier" ::: "memory")
#define BAR_PLAIN asm volatile("s_barrier" ::: "memory")

// fp32 -> bf16 round-to-nearest-even
__device__ __forceinline__ u16 f2bf(float f) {
  union { float f; uint32_t u; } v; v.f = f;
  uint32_t u = v.u;
  u += 0x7fffu + ((u >> 16) & 1u);
  return (u16)(u >> 16);
}
__device__ __forceinline__ float bf2f(u16 u) {
  union { uint32_t u; float f; } v; v.u = ((uint32_t)u) << 16; return v.f;
}

// pack 4 fp32 -> 4 bf16 (truncation) via 2 v_perm_b32
__device__ __forceinline__ short4v pack4bf(float a, float b, float c, float d) {
  union { uint32_t u[2]; short4v s; } r;
  r.u[0] = __builtin_amdgcn_perm(__float_as_uint(b), __float_as_uint(a), 0x07060302u);
  r.u[1] = __builtin_amdgcn_perm(__float_as_uint(d), __float_as_uint(c), 0x07060302u);
  return r.s;
}

// async global->LDS, 16B per lane; lds dest wave-uniform (lane i -> lds + i*16B)
__device__ __forceinline__ void gld_lds16(const u16* g, u16* lds) {
  __builtin_amdgcn_global_load_lds(
      (const __attribute__((address_space(1))) uint32_t*)g,
      (__attribute__((address_space(3))) uint32_t*)lds,
      16, 0, 0);
}

// ---------------- cast: x, Wk, Wq, Wv, Wp -> bf16 ----------------
__global__ __launch_bounds__(256) void cast_all(
    const float* __restrict__ x,  const float* __restrict__ wk,
    const float* __restrict__ wq, const float* __restrict__ wv,
    const float* __restrict__ wp,
    u16* __restrict__ xb, u16* __restrict__ wkb, u16* __restrict__ wqb,
    u16* __restrict__ wvb, u16* __restrict__ wpb) {
  const int NX = NM * NC / 4;
  const int NW = NC * NC / 4;
  int i = blockIdx.x * 256 + threadIdx.x;
  const float* src; u16* dst; int off;
  if (i < NX)            { src = x;  dst = xb;  off = i; }
  else if (i < NX+NW)    { src = wk; dst = wkb; off = i - NX; }
  else if (i < NX+2*NW)  { src = wq; dst = wqb; off = i - NX - NW; }
  else if (i < NX+3*NW)  { src = wv; dst = wvb; off = i - NX - 2*NW; }
  else if (i < NX+4*NW)  { src = wp; dst = wpb; off = i - NX - 3*NW; }
  else return;
  float4v f = ((const float4v*)src)[off];
  short4v o;
  o.x = (short)f2bf(f.x); o.y = (short)f2bf(f.y);
  o.z = (short)f2bf(f.z); o.w = (short)f2bf(f.w);
  ((short4v*)dst)[off] = o;
}

// ---------------- shared 128x128xK GEMM core: C = A * W^T ----------------
__device__ __forceinline__ void gemm_tile(
    const u16* __restrict__ A_tile, const u16* __restrict__ W_tile,
    u16* As, u16* Bs, float4v (&acc)[4][4]) {
  const int tid  = threadIdx.x;
  const int wave = tid >> 6, lane = tid & 63;
  const int quad = lane >> 4, l15 = lane & 15;
  const int wm = wave >> 1, wn = wave & 1;
  const int c8 = lane & 7, r8 = lane >> 3;

#pragma unroll
  for (int i = 0; i < 4; i++)
#pragma unroll
    for (int j = 0; j < 4; j++) acc[i][j] = (float4v){0.f, 0.f, 0.f, 0.f};

  for (int k0 = 0; k0 < NC; k0 += 64) {
#pragma unroll
    for (int i = 0; i < 4; i++) {
      int row = wave * 32 + i * 8 + r8;
      int gc  = c8 ^ (row & 7);
      gld_lds16(A_tile + row * NC + k0 + gc * 8, As + (wave * 32 + i * 8) * 64);
      gld_lds16(W_tile + row * NC + k0 + gc * 8, Bs + (wave * 32 + i * 8) * 64);
    }
    __syncthreads();
#pragma unroll
    for (int kk = 0; kk < 2; kk++) {
      short8 af[4], bf[4];
#pragma unroll
      for (int mt = 0; mt < 4; mt++) {
        int row = wm * 64 + mt * 16 + l15;
        int ch  = (kk * 4 + quad) ^ (row & 7);
        af[mt] = *(const short8*)(As + row * 64 + ch * 8);
      }
#pragma unroll
      for (int nt = 0; nt < 4; nt++) {
        int row = wn * 64 + nt * 16 + l15;
        int ch  = (kk * 4 + quad) ^ (row & 7);
        bf[nt] = *(const short8*)(Bs + row * 64 + ch * 8);
      }
#pragma unroll
      for (int mt = 0; mt < 4; mt++)
#pragma unroll
        for (int nt = 0; nt < 4; nt++)
          acc[mt][nt] = __builtin_amdgcn_mfma_f32_16x16x32_bf16(af[mt], bf[nt], acc[mt][nt], 0, 0, 0);
    }
    __syncthreads();
  }
}

// ---------------- fused QKV projection + in-kernel V transpose ----------------
// 1D grid 768. XCD = id%8 owns n-tile (id%8) of all 3 W matrices (L2-resident).
// Q pre-scaled by 0.125*log2e. V blocks write Vt[b,h,d,t'] directly via LDS
// transpose (s-permuted within 64-t chunks to match attn's PV fragment layout).
__global__ __launch_bounds__(256) void qkv_gemm(
    const u16* __restrict__ xb,
    const u16* __restrict__ wqb, const u16* __restrict__ wkb, const u16* __restrict__ wvb,
    const float* __restrict__ bq, const float* __restrict__ bk, const float* __restrict__ bv,
    u16* __restrict__ Q, u16* __restrict__ K, u16* __restrict__ Vt) {
  __shared__ u16 S[2][128 * 64];     // As | Bs, contiguous 32 KB (reused for V transpose)
  const int id  = blockIdx.x;
  const int x8  = id & 7;            // n-tile (and XCD)
  const int rr  = id >> 3;
  const int mti = rr & 31;           // m tile
  const int mat = rr >> 5;           // 0=Q 1=K 2=V
  const int n0  = x8 * 128;
  const int m0  = mti * 128;
  const u16*   W    = (mat == 0) ? wqb : (mat == 1) ? wkb : wvb;
  const float* bias = (mat == 0) ? bq  : (mat == 1) ? bk  : bv;

  float4v acc[4][4];
  gemm_tile(xb + m0 * NC, W + n0 * NC, S[0], S[1], acc);

  const int tid = threadIdx.x, wave = tid >> 6, lane = tid & 63;
  const int quad = lane >> 4, l15 = lane & 15;
  const int wm = wave >> 1, wn = wave & 1;

  if (mat != 2) {
    u16* dst = (mat == 0) ? Q : K;
    const float osc = (mat == 0) ? 0.18033688f : 1.0f;   // fold 0.125*log2(e) into Q
#pragma unroll
    for (int nt = 0; nt < 4; nt++) {
      int col = n0 + wn * 64 + nt * 16 + l15;
      float bval = bias[col];
#pragma unroll
      for (int mt = 0; mt < 4; mt++) {
        int rowb = m0 + wm * 64 + mt * 16 + quad * 4;
#pragma unroll
        for (int r = 0; r < 4; r++)
          dst[(size_t)(rowb + r) * NC + col] = f2bf((acc[mt][nt][r] + bval) * osc);
      }
    }
  } else {
    // V: transpose + s-permute via LDS. tile[c][off]: c = local col (2 heads x 64 d),
    // off = chunk*64 + p(s), p = quad*16 + mt*4 + r. 16-chunk XOR swizzle by (c&15).
    u16* tile = (u16*)S;
#pragma unroll
    for (int nt = 0; nt < 4; nt++) {
      int c = wn * 64 + nt * 16 + l15;
      float bval = bias[n0 + c];
#pragma unroll
      for (int mt = 0; mt < 4; mt++) {
#pragma unroll
        for (int r = 0; r < 4; r++) {
          int mr  = mt * 4 + r;
          int off = wm * 64 + quad * 16 + mr;          // permuted t position
          int ck  = (off >> 3) ^ (c & 15);
          tile[c * 128 + ck * 8 + (off & 7)] = f2bf(acc[mt][nt][r] + bval);
        }
      }
    }
    __syncthreads();
    const int b  = m0 >> 11, t0 = m0 & 2047;
    const int bh0 = b * NH + (n0 >> 6);
#pragma unroll
    for (int it = 0; it < 8; it++) {
      int idx = it * 256 + tid;      // 0..2047 chunks of 16 B
      int c = idx >> 4, ck = idx & 15;
      short8 v = *(const short8*)(tile + c * 128 + ((ck ^ (c & 15)) * 8));
      *(short8*)(Vt + ((size_t)(bh0 + (c >> 6)) * ND + (c & 63)) * NT + t0 + ck * 8) = v;
    }
  }
}

// ---------------- flash attention (causal), fixed-max softmax, 32 classes/bh ----
// Q pre-scaled by 0.125*log2e -> p = exp2(qk) directly; linear split merge.
// Classes: tiles 0..4 whole (2..10 iters); 5..10 split x2 (6..11); 11..15 x3 (8..11).
// grid 1024 = 8 XCD * 32 classes * 4 bh -> exactly 4 blocks/CU co-resident.
__global__ __launch_bounds__(256, 4) void attn(
    const u16* __restrict__ Q, const u16* __restrict__ K,
    const u16* __restrict__ Vt, u16* __restrict__ O,
    u16* __restrict__ Opart, float* __restrict__ Lpart) {
  __shared__ u16 Kc[2][64 * 64];   // [s][d] swizzled
  __shared__ u16 Vc[2][64 * 64];   // [d][pos(s)] swizzled

  const int tid = threadIdx.x, wave = tid >> 6, lane = tid & 63;
  const int quad = lane >> 4, l15 = lane & 15;
  const int c8 = lane & 7, r8 = lane >> 3;
  const int id = blockIdx.x;
  const int rr = id >> 3;
  const int cls = rr & 31;
  const int bh = (id & 7) + 8 * (rr >> 5);
  const int b = bh >> 4, h = bh & 15;

  int tile, k, c_lo, c_hi, sbase;
  if (cls < 5)        { tile = cls;
                        c_lo = 0; c_hi = 2 * tile + 1; sbase = -1; }
  else if (cls < 17)  { tile = 5 + ((cls - 5) >> 1); k = (cls - 5) & 1;
                        int half = tile + 1;
                        c_lo = k * half; c_hi = c_lo + half - 1;
                        sbase = (tile - 5) * 2 + k; }
  else                { int d3 = cls - 17; int t3 = d3 / 3; k = d3 - 3 * t3;
                        tile = 11 + t3; int C = 2 * tile + 2;
                        c_lo = (k * C) / 3; c_hi = ((k + 1) * C) / 3 - 1;
                        sbase = 12 + t3 * 3 + k; }
  const bool partial = (sbase >= 0);
  const int qb0 = tile * 128 + wave * 32;

  short8 qf[2][2];
#pragma unroll
  for (int j = 0; j < 2; j++) {
    const u16* qrow = Q + (size_t)(b * NT + qb0 + j * 16 + l15) * NC + h * ND + quad * 8;
    qf[j][0] = *(const short8*)(qrow);
    qf[j][1] = *(const short8*)(qrow + 32);
  }

  float l_c[2] = {0.f, 0.f};       // per-lane quad-partial sums
  float4v o_acc[2][4];
#pragma unroll
  for (int j = 0; j < 2; j++)
#pragma unroll
    for (int dt = 0; dt < 4; dt++) o_acc[j][dt] = (float4v){0.f, 0.f, 0.f, 0.f};

  int kOff[2], vOff[2], ldsOff[2];
#pragma unroll
  for (int ii = 0; ii < 2; ii++) {
    int row = wave * 16 + ii * 8 + r8;
    int gc  = c8 ^ (row & 7);
    kOff[ii]   = row * NC + gc * 8;
    vOff[ii]   = row * NT + gc * 8;
    ldsOff[ii] = (wave * 16 + ii * 8) * 64;
  }
  const u16* Kbase = K  + (size_t)b * NT * NC + h * ND;
  const u16* Vbase = Vt + (size_t)bh * ND * NT;

  auto stage = [&](int ci) {
    const int p = (ci - c_lo) & 1;
    const u16* kc = Kbase + (size_t)ci * (64 * NC);
    const u16* vc = Vbase + ci * 64;
#pragma unroll
    for (int ii = 0; ii < 2; ii++) {
      gld_lds16(kc + kOff[ii], Kc[p] + ldsOff[ii]);
      gld_lds16(vc + vOff[ii], Vc[p] + ldsOff[ii]);
    }
  };

  stage(c_lo);
  for (int i = c_lo; i <= c_hi; i++) {
    const int p = (i - c_lo) & 1;
    if (i < c_hi) { stage(i + 1); WB4; } else { WB0; }
    const u16* Ks = Kc[p];
    const u16* Vs = Vc[p];

    // per (j,sub): QK^T -> exp2 -> pack -> PV. Independent chains (no running max).
    short4v pf[2][4];
#pragma unroll
    for (int sub = 0; sub < 4; sub++) {
      float4v a0 = (float4v){0.f, 0.f, 0.f, 0.f};
      float4v a1 = (float4v){0.f, 0.f, 0.f, 0.f};
#pragma unroll
      for (int kk = 0; kk < 2; kk++) {
        int row = sub * 16 + l15;
        int ch  = (kk * 4 + quad) ^ (row & 7);
        short8 kf = *(const short8*)(Ks + row * 64 + ch * 8);
        a0 = __builtin_amdgcn_mfma_f32_16x16x32_bf16(kf, qf[0][kk], a0, 0, 0, 0);
        a1 = __builtin_amdgcn_mfma_f32_16x16x32_bf16(kf, qf[1][kk], a1, 0, 0, 0);
      }
#pragma unroll
      for (int j = 0; j < 2; j++) {
        const float4v& a = (j == 0) ? a0 : a1;
        const bool mj = (i * 64 + 63) > (qb0 + j * 16);   // wave-uniform diag check
        const int qg = qb0 + j * 16 + l15;
        float pv[4];
#pragma unroll
        for (int r = 0; r < 4; r++) {
          float pp = exp2f(a[r]);
          if (mj) {
            int sg = i * 64 + sub * 16 + quad * 4 + r;
            if (sg > qg) pp = 0.f;
          }
          pv[r] = pp;
        }
        l_c[j] += (pv[0] + pv[1]) + (pv[2] + pv[3]);
        pf[j][sub] = pack4bf(pv[0], pv[1], pv[2], pv[3]);
      }
    }

    // O^T += V^T * P^T : vf = 2 b128/dt (permuted layout), shared by both subtiles
#pragma unroll
    for (int dt = 0; dt < 4; dt++) {
      int row = dt * 16 + l15;
      int swz = row & 7;
      short8 vA = *(const short8*)(Vs + row * 64 + ((2 * quad)     ^ swz) * 8); // subs 0,1
      short8 vB = *(const short8*)(Vs + row * 64 + ((2 * quad + 1) ^ swz) * 8); // subs 2,3
      short4v vA0 = __builtin_shufflevector(vA, vA, 0, 1, 2, 3);
      short4v vA1 = __builtin_shufflevector(vA, vA, 4, 5, 6, 7);
      short4v vB0 = __builtin_shufflevector(vB, vB, 0, 1, 2, 3);
      short4v vB1 = __builtin_shufflevector(vB, vB, 4, 5, 6, 7);
#pragma unroll
      for (int j = 0; j < 2; j++) {
        o_acc[j][dt] = MFMA16(vA0, pf[j][0], o_acc[j][dt]);
        o_acc[j][dt] = MFMA16(vA1, pf[j][1], o_acc[j][dt]);
        o_acc[j][dt] = MFMA16(vB0, pf[j][2], o_acc[j][dt]);
        o_acc[j][dt] = MFMA16(vB1, pf[j][3], o_acc[j][dt]);
      }
    }
    if (i < c_hi) BAR_PLAIN;   // protect double buffer from next iter's DMA
  }

  // finalize l: sum the 4 quad-partials per column
  float l_tot[2];
#pragma unroll
  for (int j = 0; j < 2; j++) {
    float t = l_c[j];
    t += __shfl_xor(t, 16);
    t += __shfl_xor(t, 32);
    l_tot[j] = t;
  }

  if (!partial) {
#pragma unroll
    for (int j = 0; j < 2; j++) {
      float inv_l = 1.f / l_tot[j];
      const size_t orow = (size_t)(b * NT + qb0 + j * 16 + l15) * NC + h * ND;
#pragma unroll
      for (int dt = 0; dt < 4; dt++)
        *(short4v*)(O + orow + dt * 16 + quad * 4) =
            pack4bf(o_acc[j][dt][0] * inv_l, o_acc[j][dt][1] * inv_l,
                    o_acc[j][dt][2] * inv_l, o_acc[j][dt][3] * inv_l);
    }
  } else {
    const int slab = bh * 27 + sbase;
    u16* ob = Opart + (size_t)slab * 8192;
#pragma unroll
    for (int j = 0; j < 2; j++) {
      const int row = wave * 32 + j * 16 + l15;
#pragma unroll
      for (int dt = 0; dt < 4; dt++)
        *(short4v*)(ob + row * 64 + dt * 16 + quad * 4) =
            pack4bf(o_acc[j][dt][0], o_acc[j][dt][1],
                    o_acc[j][dt][2], o_acc[j][dt][3]);   // unnormalized partial
      if (quad == 0)
        Lpart[slab * 128 + row] = l_tot[j];
    }
  }
}

// ---------------- combine split partials (linear: fixed softmax base) ----------------
// tiles 5..10: 2 segments; tiles 11..15: 3 segments. O = sum(O_seg) / sum(l_seg).
__global__ __launch_bounds__(256) void combine(
    const u16* __restrict__ Opart, const float* __restrict__ Lp, u16* __restrict__ O) {
  int idx  = blockIdx.x * 256 + threadIdx.x;   // 0 .. 352*8192-1
  int tIdx = idx >> 13;                        // (bh, tile-5) pair, 0..351
  int rem  = idx & 8191;
  int row  = rem >> 6, d = rem & 63;
  int bh   = tIdx / 11;
  int tt   = tIdx - bh * 11;                   // 0..10 -> tile 5..15
  int tile = 5 + tt;
  int S, sb;
  if (tile < 11) { S = 2; sb = (tile - 5) * 2; }
  else           { S = 3; sb = 12 + (tile - 11) * 3; }
  int slab0 = bh * 27 + sb;
  float osum = 0.f, lsum = 0.f;
  for (int s = 0; s < S; s++) {
    osum += bf2f(Opart[(size_t)(slab0 + s) * 8192 + rem]);
    lsum += Lp[(slab0 + s) * 128 + row];
  }
  int b = bh >> 4, h = bh & 15;
  int t = tile * 128 + row;
  O[(size_t)(b * NT + t) * NC + h * ND + d] = f2bf(osum / lsum);
}

// ---------------- output projection: 64x128 tiles ----------------
__global__ __launch_bounds__(256) void out_gemm(
    const u16* __restrict__ Ob, const u16* __restrict__ wpb,
    const float* __restrict__ bp, float* __restrict__ out) {
  __shared__ u16 As[64 * 64];
  __shared__ u16 Bs[128 * 64];
  const int n0 = blockIdx.x * 128;
  const int m0 = blockIdx.y * 64;
  const int tid = threadIdx.x, wave = tid >> 6, lane = tid & 63;
  const int quad = lane >> 4, l15 = lane & 15;
  const int wm = wave >> 1, wn = wave & 1;
  const int c8 = lane & 7, r8 = lane >> 3;

  float4v acc[2][4];
#pragma unroll
  for (int i = 0; i < 2; i++)
#pragma unroll
    for (int j = 0; j < 4; j++) acc[i][j] = (float4v){0.f, 0.f, 0.f, 0.f};

  for (int k0 = 0; k0 < NC; k0 += 64) {
#pragma unroll
    for (int i = 0; i < 2; i++) {
      int row = wave * 16 + i * 8 + r8;
      int gc  = c8 ^ (row & 7);
      gld_lds16(Ob + (size_t)(m0 + row) * NC + k0 + gc * 8, As + (wave * 16 + i * 8) * 64);
    }
#pragma unroll
    for (int i = 0; i < 4; i++) {
      int row = wave * 32 + i * 8 + r8;
      int gc  = c8 ^ (row & 7);
      gld_lds16(wpb + (size_t)(n0 + row) * NC + k0 + gc * 8, Bs + (wave * 32 + i * 8) * 64);
    }
    __syncthreads();
#pragma unroll
    for (int kk = 0; kk < 2; kk++) {
      short8 af[2], bf[4];
#pragma unroll
      for (int mt = 0; mt < 2; mt++) {
        int row = wm * 32 + mt * 16 + l15;
        int ch  = (kk * 4 + quad) ^ (row & 7);
        af[mt] = *(const short8*)(As + row * 64 + ch * 8);
      }
#pragma unroll
      for (int nt = 0; nt < 4; nt++) {
        int row = wn * 64 + nt * 16 + l15;
        int ch  = (kk * 4 + quad) ^ (row & 7);
        bf[nt] = *(const short8*)(Bs + row * 64 + ch * 8);
      }
#pragma unroll
      for (int mt = 0; mt < 2; mt++)
#pragma unroll
        for (int nt = 0; nt < 4; nt++)
          acc[mt][nt] = __builtin_amdgcn_mfma_f32_16x16x32_bf16(af[mt], bf[nt], acc[mt][nt], 0, 0, 0);
    }
    __syncthreads();
  }

#pragma unroll
  for (int nt = 0; nt < 4; nt++) {
    int col = n0 + wn * 64 + nt * 16 + l15;
    float bval = bp[col];
#pragma unroll
    for (int mt = 0; mt < 2; mt++) {
      int rowb = m0 + wm * 32 + mt * 16 + quad * 4;
#pragma unroll
      for (int r = 0; r < 4; r++)
        out[(rowb + r) * NC + col] = acc[mt][nt][r] + bval;
    }
  }
}

extern "C" void kernel_launch(void* const* d_in, const int* in_sizes, int n_in,
                              void* d_out, int out_size, void* d_ws, size_t ws_size,
                              hipStream_t stream) {
  // setup_inputs order: x, Wk, bk, Wq, bq, Wv, bv, Wp, bp
  const float* x  = (const float*)d_in[0];
  const float* Wk = (const float*)d_in[1];
  const float* bk = (const float*)d_in[2];
  const float* Wq = (const float*)d_in[3];
  const float* bq = (const float*)d_in[4];
  const float* Wv = (const float*)d_in[5];
  const float* bv = (const float*)d_in[6];
  const float* Wp = (const float*)d_in[7];
  const float* bp = (const float*)d_in[8];
  float* out = (float*)d_out;

  uint8_t* ws = (uint8_t*)d_ws;
  const size_t MB = 1u << 20;
  // layout: xb[0,8) wk[8,10) wq[10,12) wv[12,14) wp[14,16) — xb/wk/wq/wv die after
  // qkv. Opart reuses [0,13.5): 27 slabs x 32 bh x 16 KB = 13.5 MB. Lpart at
  // [13.5,13.93) (within dead wv region). wpb [14,16) stays live for out_gemm.
  u16* xb    = (u16*)(ws + 0 * MB);
  u16* wkb   = (u16*)(ws + 8 * MB);
  u16* wqb   = (u16*)(ws + 10 * MB);
  u16* wvb   = (u16*)(ws + 12 * MB);
  u16* wpb   = (u16*)(ws + 14 * MB);
  u16* Qb    = (u16*)(ws + 16 * MB);
  u16* Kb    = (u16*)(ws + 24 * MB);
  u16* Vtb   = (u16*)(ws + 32 * MB);   // [B,H,D,T'] (s-permuted in 64-chunks)
  u16* Ob    = (u16*)(ws + 40 * MB);   // attention output
  u16* Opart = (u16*)(ws + 0 * MB);    // 864 slabs * 16 KB = 13.5 MB
  float* Lpart = (float*)(ws + 13 * MB + 512 * 1024);   // 864*128*4 = 442 KB

  cast_all<<<8192, 256, 0, stream>>>(x, Wk, Wq, Wv, Wp, xb, wkb, wqb, wvb, wpb);
  qkv_gemm<<<768, 256, 0, stream>>>(xb, wqb, wkb, wvb, bq, bk, bv, Qb, Kb, Vtb);
  attn<<<1024, 256, 0, stream>>>(Qb, Kb, Vtb, Ob, Opart, Lpart);
  combine<<<11264, 256, 0, stream>>>(Opart, Lpart, Ob);
  out_gemm<<<dim3(8, 64), 256, 0, stream>>>(Ob, wpb, bp, out);
}

// Round 9
// 198.731 us; speedup vs baseline: 1.1306x; 1.1306x over previous
//
#include <hip/hip_runtime.h>
#include <stdint.h>

typedef unsigned short u16;
typedef __attribute__((ext_vector_type(8))) short short8;   // 8 bf16 (4 VGPRs) MFMA A/B frag K=32
typedef __attribute__((ext_vector_type(4))) short short4v;  // 4 bf16 (2 VGPRs) MFMA A/B frag K=16
typedef __attribute__((ext_vector_type(4))) float float4v;  // MFMA C/D frag

#define NB 2
#define NT 2048
#define NC 1024
#define NH 16
#define ND 64
#define NM (NB*NT)   // 4096 rows total

// 16x16x16 bf16 MFMA (2-VGPR operands). Builtin if present, else raw asm.
#if defined(__has_builtin)
#if __has_builtin(__builtin_amdgcn_mfma_f32_16x16x16bf16_1k)
#define MFMA16(a, b, c) __builtin_amdgcn_mfma_f32_16x16x16bf16_1k(a, b, c, 0, 0, 0)
#endif
#endif
#ifndef MFMA16
static __device__ __forceinline__ float4v mfma16_asm(short4v a, short4v b, float4v c) {
  asm volatile("v_mfma_f32_16x16x16_bf16 %0, %1, %2, %0" : "+v"(c) : "v"(a), "v"(b));
  return c;
}
#define MFMA16(a, b, c) mfma16_asm(a, b, c)
#endif

// wait-for-own-chunk + barrier. vmcnt(N) = the N just-issued next-chunk loads stay in flight.
#define WB4 asm volatile("s_waitcnt vmcnt(4)\n\ts_barrier" ::: "memory")
#define WB3 asm volatile("s_waitcnt vmcnt(3)\n\ts_barrier" ::: "memory")
#define WB0 asm volatile("s_waitcnt vmcnt(0)\n\ts_barrier" ::: "memory")
#define BAR_PLAIN asm volatile("s_barrier" ::: "memory")

// fp32 -> bf16 round-to-nearest-even
__device__ __forceinline__ u16 f2bf(float f) {
  union { float f; uint32_t u; } v; v.f = f;
  uint32_t u = v.u;
  u += 0x7fffu + ((u >> 16) & 1u);
  return (u16)(u >> 16);
}
__device__ __forceinline__ float bf2f(u16 u) {
  union { uint32_t u; float f; } v; v.u = ((uint32_t)u) << 16; return v.f;
}

// pack 4 fp32 -> 4 bf16 (truncation) via 2 v_perm_b32
__device__ __forceinline__ short4v pack4bf(float a, float b, float c, float d) {
  union { uint32_t u[2]; short4v s; } r;
  r.u[0] = __builtin_amdgcn_perm(__float_as_uint(b), __float_as_uint(a), 0x07060302u);
  r.u[1] = __builtin_amdgcn_perm(__float_as_uint(d), __float_as_uint(c), 0x07060302u);
  return r.s;
}

// async global->LDS, 16B per lane; lds dest wave-uniform (lane i -> lds + i*16B)
__device__ __forceinline__ void gld_lds16(const u16* g, u16* lds) {
  __builtin_amdgcn_global_load_lds(
      (const __attribute__((address_space(1))) uint32_t*)g,
      (__attribute__((address_space(3))) uint32_t*)lds,
      16, 0, 0);
}

// ---------------- cast: x, Wk, Wq, Wv, Wp -> bf16 ----------------
__global__ __launch_bounds__(256) void cast_all(
    const float* __restrict__ x,  const float* __restrict__ wk,
    const float* __restrict__ wq, const float* __restrict__ wv,
    const float* __restrict__ wp,
    u16* __restrict__ xb, u16* __restrict__ wkb, u16* __restrict__ wqb,
    u16* __restrict__ wvb, u16* __restrict__ wpb) {
  const int NX = NM * NC / 4;
  const int NW = NC * NC / 4;
  int i = blockIdx.x * 256 + threadIdx.x;
  const float* src; u16* dst; int off;
  if (i < NX)            { src = x;  dst = xb;  off = i; }
  else if (i < NX+NW)    { src = wk; dst = wkb; off = i - NX; }
  else if (i < NX+2*NW)  { src = wq; dst = wqb; off = i - NX - NW; }
  else if (i < NX+3*NW)  { src = wv; dst = wvb; off = i - NX - 2*NW; }
  else if (i < NX+4*NW)  { src = wp; dst = wpb; off = i - NX - 3*NW; }
  else return;
  float4v f = ((const float4v*)src)[off];
  short4v o;
  o.x = (short)f2bf(f.x); o.y = (short)f2bf(f.y);
  o.z = (short)f2bf(f.z); o.w = (short)f2bf(f.w);
  ((short4v*)dst)[off] = o;
}

// ---------------- fused QKV projection + in-kernel V transpose (PIPELINED) ----------
// 1D grid 768. XCD = id%8 owns n-tile (id%8) of all 3 W matrices (L2-resident).
// BK=32, double-buffered LDS, WB4 fine-grained waits (prefetch stays in flight).
// Q pre-scaled by 0.125*log2e. V blocks write Vt[b,h,d,t'] via LDS transpose.
__global__ __launch_bounds__(256, 4) void qkv_gemm(
    const u16* __restrict__ xb,
    const u16* __restrict__ wqb, const u16* __restrict__ wkb, const u16* __restrict__ wvb,
    const float* __restrict__ bq, const float* __restrict__ bk, const float* __restrict__ bv,
    u16* __restrict__ Q, u16* __restrict__ K, u16* __restrict__ Vt) {
  __shared__ u16 S[4][128 * 32];     // As[0] As[1] Bs[0] Bs[1] = 32 KB contiguous
  const int id  = blockIdx.x;
  const int x8  = id & 7;            // n-tile (and XCD)
  const int rr  = id >> 3;
  const int mti = rr & 31;           // m tile
  const int mat = rr >> 5;           // 0=Q 1=K 2=V
  const int n0  = x8 * 128;
  const int m0  = mti * 128;
  const u16*   W    = (mat == 0) ? wqb : (mat == 1) ? wkb : wvb;
  const float* bias = (mat == 0) ? bq  : (mat == 1) ? bk  : bv;

  const int tid = threadIdx.x, wave = tid >> 6, lane = tid & 63;
  const int quad = lane >> 4, l15 = lane & 15;
  const int wm = wave >> 1, wn = wave & 1;

  const u16* A_tile = xb + (size_t)m0 * NC;
  const u16* W_tile = W  + (size_t)n0 * NC;

  // staging: thread t covers row (ii*64 + wave*16 + (lane>>2)), chunk (lane&3)^(row&3)
  const int srow = wave * 16 + (lane >> 2);
  const int sgc  = (lane & 3) ^ (srow & 3);
  const int soff = srow * NC + sgc * 8;
  const int ldsb0 = wave * 16 * 32;          // wave-uniform LDS bases
  const int ldsb1 = (64 + wave * 16) * 32;

  float4v acc[4][4];
#pragma unroll
  for (int i = 0; i < 4; i++)
#pragma unroll
    for (int j = 0; j < 4; j++) acc[i][j] = (float4v){0.f, 0.f, 0.f, 0.f};

  auto stage = [&](int ki, int p) {
    const u16* a = A_tile + ki * 32;
    const u16* w = W_tile + ki * 32;
    gld_lds16(a + soff,           S[p]     + ldsb0);
    gld_lds16(a + 64 * NC + soff, S[p]     + ldsb1);
    gld_lds16(w + soff,           S[2 + p] + ldsb0);
    gld_lds16(w + 64 * NC + soff, S[2 + p] + ldsb1);
  };

  stage(0, 0);
  for (int ki = 0; ki < 32; ki++) {
    const int p = ki & 1;
    if (ki < 31) { stage(ki + 1, p ^ 1); WB4; } else { WB0; }
    const u16* As = S[p];
    const u16* Bs = S[2 + p];
    short8 af[4], bf[4];
#pragma unroll
    for (int mt = 0; mt < 4; mt++) {
      int row = wm * 64 + mt * 16 + l15;
      int e   = quad ^ (row & 3);
      af[mt] = *(const short8*)(As + row * 32 + e * 8);
    }
#pragma unroll
    for (int nt = 0; nt < 4; nt++) {
      int row = wn * 64 + nt * 16 + l15;
      int e   = quad ^ (row & 3);
      bf[nt] = *(const short8*)(Bs + row * 32 + e * 8);
    }
#pragma unroll
    for (int mt = 0; mt < 4; mt++)
#pragma unroll
      for (int nt = 0; nt < 4; nt++)
        acc[mt][nt] = __builtin_amdgcn_mfma_f32_16x16x32_bf16(af[mt], bf[nt], acc[mt][nt], 0, 0, 0);
    if (ki < 31) BAR_PLAIN;   // protect buffer p^1 (now being DMA'd) ordering
  }

  if (mat != 2) {
    u16* dst = (mat == 0) ? Q : K;
    const float osc = (mat == 0) ? 0.18033688f : 1.0f;   // fold 0.125*log2(e) into Q
#pragma unroll
    for (int nt = 0; nt < 4; nt++) {
      int col = n0 + wn * 64 + nt * 16 + l15;
      float bval = bias[col];
#pragma unroll
      for (int mt = 0; mt < 4; mt++) {
        int rowb = m0 + wm * 64 + mt * 16 + quad * 4;
#pragma unroll
        for (int r = 0; r < 4; r++)
          dst[(size_t)(rowb + r) * NC + col] = f2bf((acc[mt][nt][r] + bval) * osc);
      }
    }
  } else {
    // V: transpose + s-permute via LDS. tile[c][off]: c = local col (2 heads x 64 d),
    // off = chunk*64 + p(s), p = quad*16 + mt*4 + r. 16-chunk XOR swizzle by (c&15).
    BAR_PLAIN;                       // all waves done reading S before reuse
    u16* tile = (u16*)S;
#pragma unroll
    for (int nt = 0; nt < 4; nt++) {
      int c = wn * 64 + nt * 16 + l15;
      float bval = bias[n0 + c];
#pragma unroll
      for (int mt = 0; mt < 4; mt++) {
#pragma unroll
        for (int r = 0; r < 4; r++) {
          int mr  = mt * 4 + r;
          int off = wm * 64 + quad * 16 + mr;          // permuted t position
          int ck  = (off >> 3) ^ (c & 15);
          tile[c * 128 + ck * 8 + (off & 7)] = f2bf(acc[mt][nt][r] + bval);
        }
      }
    }
    __syncthreads();
    const int b  = m0 >> 11, t0 = m0 & 2047;
    const int bh0 = b * NH + (n0 >> 6);
#pragma unroll
    for (int it = 0; it < 8; it++) {
      int idx = it * 256 + tid;      // 0..2047 chunks of 16 B
      int c = idx >> 4, ck = idx & 15;
      short8 v = *(const short8*)(tile + c * 128 + ((ck ^ (c & 15)) * 8));
      *(short8*)(Vt + ((size_t)(bh0 + (c >> 6)) * ND + (c & 63)) * NT + t0 + ck * 8) = v;
    }
  }
}

// ---------------- flash attention (causal), fixed-max softmax, 32 classes/bh ----
// Q pre-scaled by 0.125*log2e -> p = exp2(qk) directly; linear split merge.
// Classes: tiles 0..4 whole (2..10 iters); 5..10 split x2 (6..11); 11..15 x3 (8..11).
// grid 1024 = 8 XCD * 32 classes * 4 bh -> exactly 4 blocks/CU co-resident.
__global__ __launch_bounds__(256, 4) void attn(
    const u16* __restrict__ Q, const u16* __restrict__ K,
    const u16* __restrict__ Vt, u16* __restrict__ O,
    u16* __restrict__ Opart, float* __restrict__ Lpart) {
  __shared__ u16 Kc[2][64 * 64];   // [s][d] swizzled
  __shared__ u16 Vc[2][64 * 64];   // [d][pos(s)] swizzled

  const int tid = threadIdx.x, wave = tid >> 6, lane = tid & 63;
  const int quad = lane >> 4, l15 = lane & 15;
  const int c8 = lane & 7, r8 = lane >> 3;
  const int id = blockIdx.x;
  const int rr = id >> 3;
  const int cls = rr & 31;
  const int bh = (id & 7) + 8 * (rr >> 5);
  const int b = bh >> 4, h = bh & 15;

  int tile, k, c_lo, c_hi, sbase;
  if (cls < 5)        { tile = cls;
                        c_lo = 0; c_hi = 2 * tile + 1; sbase = -1; }
  else if (cls < 17)  { tile = 5 + ((cls - 5) >> 1); k = (cls - 5) & 1;
                        int half = tile + 1;
                        c_lo = k * half; c_hi = c_lo + half - 1;
                        sbase = (tile - 5) * 2 + k; }
  else                { int d3 = cls - 17; int t3 = d3 / 3; k = d3 - 3 * t3;
                        tile = 11 + t3; int C = 2 * tile + 2;
                        c_lo = (k * C) / 3; c_hi = ((k + 1) * C) / 3 - 1;
                        sbase = 12 + t3 * 3 + k; }
  const bool partial = (sbase >= 0);
  const int qb0 = tile * 128 + wave * 32;

  short8 qf[2][2];
#pragma unroll
  for (int j = 0; j < 2; j++) {
    const u16* qrow = Q + (size_t)(b * NT + qb0 + j * 16 + l15) * NC + h * ND + quad * 8;
    qf[j][0] = *(const short8*)(qrow);
    qf[j][1] = *(const short8*)(qrow + 32);
  }

  float l_c[2] = {0.f, 0.f};       // per-lane quad-partial sums
  float4v o_acc[2][4];
#pragma unroll
  for (int j = 0; j < 2; j++)
#pragma unroll
    for (int dt = 0; dt < 4; dt++) o_acc[j][dt] = (float4v){0.f, 0.f, 0.f, 0.f};

  int kOff[2], vOff[2], ldsOff[2];
#pragma unroll
  for (int ii = 0; ii < 2; ii++) {
    int row = wave * 16 + ii * 8 + r8;
    int gc  = c8 ^ (row & 7);
    kOff[ii]   = row * NC + gc * 8;
    vOff[ii]   = row * NT + gc * 8;
    ldsOff[ii] = (wave * 16 + ii * 8) * 64;
  }
  const u16* Kbase = K  + (size_t)b * NT * NC + h * ND;
  const u16* Vbase = Vt + (size_t)bh * ND * NT;

  auto stage = [&](int ci) {
    const int p = (ci - c_lo) & 1;
    const u16* kc = Kbase + (size_t)ci * (64 * NC);
    const u16* vc = Vbase + ci * 64;
#pragma unroll
    for (int ii = 0; ii < 2; ii++) {
      gld_lds16(kc + kOff[ii], Kc[p] + ldsOff[ii]);
      gld_lds16(vc + vOff[ii], Vc[p] + ldsOff[ii]);
    }
  };

  stage(c_lo);
  for (int i = c_lo; i <= c_hi; i++) {
    const int p = (i - c_lo) & 1;
    if (i < c_hi) { stage(i + 1); WB4; } else { WB0; }
    const u16* Ks = Kc[p];
    const u16* Vs = Vc[p];

    // per (j,sub): QK^T -> exp2 -> pack -> PV. Independent chains (no running max).
    short4v pf[2][4];
#pragma unroll
    for (int sub = 0; sub < 4; sub++) {
      float4v a0 = (float4v){0.f, 0.f, 0.f, 0.f};
      float4v a1 = (float4v){0.f, 0.f, 0.f, 0.f};
#pragma unroll
      for (int kk = 0; kk < 2; kk++) {
        int row = sub * 16 + l15;
        int ch  = (kk * 4 + quad) ^ (row & 7);
        short8 kf = *(const short8*)(Ks + row * 64 + ch * 8);
        a0 = __builtin_amdgcn_mfma_f32_16x16x32_bf16(kf, qf[0][kk], a0, 0, 0, 0);
        a1 = __builtin_amdgcn_mfma_f32_16x16x32_bf16(kf, qf[1][kk], a1, 0, 0, 0);
      }
#pragma unroll
      for (int j = 0; j < 2; j++) {
        const float4v& a = (j == 0) ? a0 : a1;
        const bool mj = (i * 64 + 63) > (qb0 + j * 16);   // wave-uniform diag check
        const int qg = qb0 + j * 16 + l15;
        float pv[4];
#pragma unroll
        for (int r = 0; r < 4; r++) {
          float pp = exp2f(a[r]);
          if (mj) {
            int sg = i * 64 + sub * 16 + quad * 4 + r;
            if (sg > qg) pp = 0.f;
          }
          pv[r] = pp;
        }
        l_c[j] += (pv[0] + pv[1]) + (pv[2] + pv[3]);
        pf[j][sub] = pack4bf(pv[0], pv[1], pv[2], pv[3]);
      }
    }

    // O^T += V^T * P^T : vf = 2 b128/dt (permuted layout), shared by both subtiles
#pragma unroll
    for (int dt = 0; dt < 4; dt++) {
      int row = dt * 16 + l15;
      int swz = row & 7;
      short8 vA = *(const short8*)(Vs + row * 64 + ((2 * quad)     ^ swz) * 8); // subs 0,1
      short8 vB = *(const short8*)(Vs + row * 64 + ((2 * quad + 1) ^ swz) * 8); // subs 2,3
      short4v vA0 = __builtin_shufflevector(vA, vA, 0, 1, 2, 3);
      short4v vA1 = __builtin_shufflevector(vA, vA, 4, 5, 6, 7);
      short4v vB0 = __builtin_shufflevector(vB, vB, 0, 1, 2, 3);
      short4v vB1 = __builtin_shufflevector(vB, vB, 4, 5, 6, 7);
#pragma unroll
      for (int j = 0; j < 2; j++) {
        o_acc[j][dt] = MFMA16(vA0, pf[j][0], o_acc[j][dt]);
        o_acc[j][dt] = MFMA16(vA1, pf[j][1], o_acc[j][dt]);
        o_acc[j][dt] = MFMA16(vB0, pf[j][2], o_acc[j][dt]);
        o_acc[j][dt] = MFMA16(vB1, pf[j][3], o_acc[j][dt]);
      }
    }
    if (i < c_hi) BAR_PLAIN;   // protect double buffer from next iter's DMA
  }

  // finalize l: sum the 4 quad-partials per column
  float l_tot[2];
#pragma unroll
  for (int j = 0; j < 2; j++) {
    float t = l_c[j];
    t += __shfl_xor(t, 16);
    t += __shfl_xor(t, 32);
    l_tot[j] = t;
  }

  if (!partial) {
#pragma unroll
    for (int j = 0; j < 2; j++) {
      float inv_l = 1.f / l_tot[j];
      const size_t orow = (size_t)(b * NT + qb0 + j * 16 + l15) * NC + h * ND;
#pragma unroll
      for (int dt = 0; dt < 4; dt++)
        *(short4v*)(O + orow + dt * 16 + quad * 4) =
            pack4bf(o_acc[j][dt][0] * inv_l, o_acc[j][dt][1] * inv_l,
                    o_acc[j][dt][2] * inv_l, o_acc[j][dt][3] * inv_l);
    }
  } else {
    const int slab = bh * 27 + sbase;
    u16* ob = Opart + (size_t)slab * 8192;
#pragma unroll
    for (int j = 0; j < 2; j++) {
      const int row = wave * 32 + j * 16 + l15;
#pragma unroll
      for (int dt = 0; dt < 4; dt++)
        *(short4v*)(ob + row * 64 + dt * 16 + quad * 4) =
            pack4bf(o_acc[j][dt][0], o_acc[j][dt][1],
                    o_acc[j][dt][2], o_acc[j][dt][3]);   // unnormalized partial
      if (quad == 0)
        Lpart[slab * 128 + row] = l_tot[j];
    }
  }
}

// ---------------- combine split partials (linear: fixed softmax base) ----------------
// tiles 5..10: 2 segments; tiles 11..15: 3 segments. O = sum(O_seg) / sum(l_seg).
__global__ __launch_bounds__(256) void combine(
    const u16* __restrict__ Opart, const float* __restrict__ Lp, u16* __restrict__ O) {
  int idx  = blockIdx.x * 256 + threadIdx.x;   // 0 .. 352*8192-1
  int tIdx = idx >> 13;                        // (bh, tile-5) pair, 0..351
  int rem  = idx & 8191;
  int row  = rem >> 6, d = rem & 63;
  int bh   = tIdx / 11;
  int tt   = tIdx - bh * 11;                   // 0..10 -> tile 5..15
  int tile = 5 + tt;
  int S, sb;
  if (tile < 11) { S = 2; sb = (tile - 5) * 2; }
  else           { S = 3; sb = 12 + (tile - 11) * 3; }
  int slab0 = bh * 27 + sb;
  float osum = 0.f, lsum = 0.f;
  for (int s = 0; s < S; s++) {
    osum += bf2f(Opart[(size_t)(slab0 + s) * 8192 + rem]);
    lsum += Lp[(slab0 + s) * 128 + row];
  }
  int b = bh >> 4, h = bh & 15;
  int t = tile * 128 + row;
  O[(size_t)(b * NT + t) * NC + h * ND + d] = f2bf(osum / lsum);
}

// ---------------- output projection: 64x128 tiles, BK=32 pipelined ----------------
__global__ __launch_bounds__(256, 5) void out_gemm(
    const u16* __restrict__ Ob, const u16* __restrict__ wpb,
    const float* __restrict__ bp, float* __restrict__ out) {
  __shared__ u16 Sa[2][64 * 32];    // 8 KB
  __shared__ u16 Sb[2][128 * 32];   // 16 KB
  const int n0 = blockIdx.x * 128;
  const int m0 = blockIdx.y * 64;
  const int tid = threadIdx.x, wave = tid >> 6, lane = tid & 63;
  const int quad = lane >> 4, l15 = lane & 15;
  const int wm = wave >> 1, wn = wave & 1;

  const u16* A_tile = Ob  + (size_t)m0 * NC;
  const u16* W_tile = wpb + (size_t)n0 * NC;
  const int srow = wave * 16 + (lane >> 2);
  const int sgc  = (lane & 3) ^ (srow & 3);
  const int soff = srow * NC + sgc * 8;
  const int ldsb0 = wave * 16 * 32;
  const int ldsb1 = (64 + wave * 16) * 32;

  float4v acc[2][4];
#pragma unroll
  for (int i = 0; i < 2; i++)
#pragma unroll
    for (int j = 0; j < 4; j++) acc[i][j] = (float4v){0.f, 0.f, 0.f, 0.f};

  auto stage = [&](int ki, int p) {
    const u16* a = A_tile + ki * 32;
    const u16* w = W_tile + ki * 32;
    gld_lds16(a + soff,           Sa[p] + ldsb0);
    gld_lds16(w + soff,           Sb[p] + ldsb0);
    gld_lds16(w + 64 * NC + soff, Sb[p] + ldsb1);
  };

  stage(0, 0);
  for (int ki = 0; ki < 32; ki++) {
    const int p = ki & 1;
    if (ki < 31) { stage(ki + 1, p ^ 1); WB3; } else { WB0; }
    short8 af[2], bf[4];
#pragma unroll
    for (int mt = 0; mt < 2; mt++) {
      int row = wm * 32 + mt * 16 + l15;
      int e   = quad ^ (row & 3);
      af[mt] = *(const short8*)(Sa[p] + row * 32 + e * 8);
    }
#pragma unroll
    for (int nt = 0; nt < 4; nt++) {
      int row = wn * 64 + nt * 16 + l15;
      int e   = quad ^ (row & 3);
      bf[nt] = *(const short8*)(Sb[p] + row * 32 + e * 8);
    }
#pragma unroll
    for (int mt = 0; mt < 2; mt++)
#pragma unroll
      for (int nt = 0; nt < 4; nt++)
        acc[mt][nt] = __builtin_amdgcn_mfma_f32_16x16x32_bf16(af[mt], bf[nt], acc[mt][nt], 0, 0, 0);
    if (ki < 31) BAR_PLAIN;
  }

#pragma unroll
  for (int nt = 0; nt < 4; nt++) {
    int col = n0 + wn * 64 + nt * 16 + l15;
    float bval = bp[col];
#pragma unroll
    for (int mt = 0; mt < 2; mt++) {
      int rowb = m0 + wm * 32 + mt * 16 + quad * 4;
#pragma unroll
      for (int r = 0; r < 4; r++)
        out[(rowb + r) * NC + col] = acc[mt][nt][r] + bval;
    }
  }
}

extern "C" void kernel_launch(void* const* d_in, const int* in_sizes, int n_in,
                              void* d_out, int out_size, void* d_ws, size_t ws_size,
                              hipStream_t stream) {
  // setup_inputs order: x, Wk, bk, Wq, bq, Wv, bv, Wp, bp
  const float* x  = (const float*)d_in[0];
  const float* Wk = (const float*)d_in[1];
  const float* bk = (const float*)d_in[2];
  const float* Wq = (const float*)d_in[3];
  const float* bq = (const float*)d_in[4];
  const float* Wv = (const float*)d_in[5];
  const float* bv = (const float*)d_in[6];
  const float* Wp = (const float*)d_in[7];
  const float* bp = (const float*)d_in[8];
  float* out = (float*)d_out;

  uint8_t* ws = (uint8_t*)d_ws;
  const size_t MB = 1u << 20;
  // layout: xb[0,8) wk[8,10) wq[10,12) wv[12,14) wp[14,16) — xb/wk/wq/wv die after
  // qkv. Opart reuses [0,13.5): 27 slabs x 32 bh x 16 KB = 13.5 MB. Lpart at
  // [13.5,13.93) (within dead wv region). wpb [14,16) stays live for out_gemm.
  u16* xb    = (u16*)(ws + 0 * MB);
  u16* wkb   = (u16*)(ws + 8 * MB);
  u16* wqb   = (u16*)(ws + 10 * MB);
  u16* wvb   = (u16*)(ws + 12 * MB);
  u16* wpb   = (u16*)(ws + 14 * MB);
  u16* Qb    = (u16*)(ws + 16 * MB);
  u16* Kb    = (u16*)(ws + 24 * MB);
  u16* Vtb   = (u16*)(ws + 32 * MB);   // [B,H,D,T'] (s-permuted in 64-chunks)
  u16* Ob    = (u16*)(ws + 40 * MB);   // attention output
  u16* Opart = (u16*)(ws + 0 * MB);    // 864 slabs * 16 KB = 13.5 MB
  float* Lpart = (float*)(ws + 13 * MB + 512 * 1024);   // 864*128*4 = 442 KB

  cast_all<<<8192, 256, 0, stream>>>(x, Wk, Wq, Wv, Wp, xb, wkb, wqb, wvb, wpb);
  qkv_gemm<<<768, 256, 0, stream>>>(xb, wqb, wkb, wvb, bq, bk, bv, Qb, Kb, Vtb);
  attn<<<1024, 256, 0, stream>>>(Qb, Kb, Vtb, Ob, Opart, Lpart);
  combine<<<11264, 256, 0, stream>>>(Opart, Lpart, Ob);
  out_gemm<<<dim3(8, 64), 256, 0, stream>>>(Ob, wpb, bp, out);
}